// Round 9
// baseline (479.492 us; speedup 1.0000x reference)
//
#include <hip/hip_runtime.h>

// MON forward-backward splitting via Anderson acceleration, MI355X/gfx950.
// R8: occupancy refactor. 1024 blocks x 256 threads (1-row strips, 3-row halo
//     LDS tile, 27.8KB). gd16 array removed (recompute) and waves_per_eu(5)
//     pins VGPR <=102 -> 5 blocks/CU = 20 waves/CU (vs 7 avg in R7's 104us
//     latency-bound iter). Packed Fhp/Gp + swizzled FhH layouts unchanged.

typedef unsigned short u16;
using short8 = __attribute__((ext_vector_type(8))) short;
using f32x4  = __attribute__((ext_vector_type(4))) float;

#define SLOT 4194304              // elements per history slot (32768 px * 128 ch)

struct Ctrl { int done; int last_slot; };

__device__ __forceinline__ u16 f2bf(float f) {
  unsigned u = __builtin_bit_cast(unsigned, f);
  unsigned r = (u + 0x7FFFu + ((u >> 16) & 1u)) >> 16;   // RNE, finite inputs
  return (u16)r;
}
__device__ __forceinline__ float bf2f(u16 h) {
  unsigned u = ((unsigned)h) << 16;
  return __builtin_bit_cast(float, u);
}

// ---------------- W[cout][cin][ky][kx] f32 -> Wb[o][cout][cin] bf16; ctrl init
__global__ void __launch_bounds__(256) k_prepw(const float* __restrict__ W,
    u16* __restrict__ Wb, Ctrl* ctrl) {
  if (blockIdx.x == 0 && threadIdx.x == 0) { ctrl->done = 0; ctrl->last_slot = 4; }
  int t = blockIdx.x * 256 + threadIdx.x;       // 9*128*128 threads
  int o = t >> 14;
  int rem = t & 16383;
  int cout = rem >> 7, cin = rem & 127;
  float v = W[(size_t)cout * 1152 + (size_t)cin * 9 + o];
  Wb[(size_t)o * 16384 + (size_t)cout * 128 + cin] = f2bf(v);
}

// ---------------- x NCHW f32 -> xsw bf16 swizzled NHWC
__global__ void __launch_bounds__(256) k_prepx(const float* __restrict__ x,
    u16* __restrict__ xsw) {
  int t = blockIdx.x * 256 + threadIdx.x;       // 524288 threads
  int g = t >> 15, p = t & 32767;
  int nb = p >> 10, gp = p & 1023, px = p & 31;
  short8 xv;
#pragma unroll
  for (int u = 0; u < 8; ++u) {
    float v = x[(size_t)nb * 131072 + (size_t)(g * 8 + u) * 1024 + gp];
    xv[u] = (short)f2bf(v);
  }
  *(short8*)(xsw + (size_t)p * 128 + (size_t)((g ^ (px & 7)) << 3)) = xv;
}

// ---------------- one Anderson iteration, fully fused ----------------
// 1024 blocks x 256 threads; lbid = 1-row strip (n = lbid>>5, y0 = lbid&31).
// Wave wv handles 32 px x 32 ch (acc[2][2]); thread owns 16 elems:
// q=(m2*2+nf)*4+rr <-> pixel p=m2*16+lhi*4+rr (x coord), ch=wv*32+nf*16+llo.
// Packed layout: Fhp/Gp elem index = (lbid*256+tid)*16 + q.
__global__ void __launch_bounds__(256)
__attribute__((amdgpu_waves_per_eu(5)))
k_iter(
    const int e,
    const u16* __restrict__ xsw, const int* __restrict__ mask_,
    const u16* __restrict__ Wb, const float* __restrict__ bias,
    float* __restrict__ Fhp, u16* __restrict__ FhH, u16* __restrict__ Gp,
    float* __restrict__ gram, float* __restrict__ gpart,
    float* __restrict__ resp, Ctrl* __restrict__ ctrl)
{
  __shared__ char smem[27776];
  char*  As       = smem;                        // 3 rows * 34 cols * 256B = 26112
  float* rowmax_s = (float*)(smem + 26112);      // [32][4] = 512
  float* rowsum_s = (float*)(smem + 26624);      // 512
  float* red      = (float*)(smem + 27136);      // 4 waves * 8 = 128
  float* alpha_s  = (float*)(smem + 27264);      // 5
  float* res_s    = (float*)(smem + 27284);      // 1
  int*   mk3      = (int*)(smem + 27392);        // 96 (rows y0-1, y0, y0+1)

  if (ctrl->done) return;

  const int tid = threadIdx.x;
  const int wv = tid >> 6, lane = tid & 63;
  const int lhi = lane >> 4, llo = lane & 15;
  const int bhw = blockIdx.x;
  const int lbid = ((bhw & 7) << 7) + (bhw >> 3);    // XCD chunk swizzle (1024=8*128)
  const int n = lbid >> 5, y0 = lbid & 31;
  const int gpix0 = (n << 10) + (y0 << 5);
  const int slot = e % 5;
  const int nact = e < 5 ? e : 5;
  const size_t base = ((size_t)lbid * 256 + tid) * 16;

  // ---- res gate (cond before body e uses res of eval e-1) ----
  if (e >= 3) {
    if (tid < 64) {
      float sd = 0.f, sf = 0.f;
      for (int i = tid; i < 1024; i += 64) { sd += resp[2 * i]; sf += resp[2 * i + 1]; }
#pragma unroll
      for (int off = 1; off < 64; off <<= 1) { sd += __shfl_xor(sd, off); sf += __shfl_xor(sf, off); }
      if (tid == 0) res_s[0] = sqrtf(sd) / (1e-5f + sqrtf(sf));
    }
    __syncthreads();
    if (res_s[0] < 1e-5f) {                      // identical decision in every block
      if (tid == 0) { ctrl->done = 1; ctrl->last_slot = (e - 1) % 5; }
      return;
    }
  }

  // ---- masks (3 rows) + gram fold of slot (e-1)%5 ----
  if (tid < 96) {
    int r = tid >> 5, xx = tid & 31;
    int gy = y0 - 1 + r;
    mk3[tid] = ((unsigned)gy < 32u) ? mask_[(n << 10) + (gy << 5) + xx] : 0;
  }
  if (e >= 1 && tid >= 96 && tid < 101) {
    int j = tid - 96;
    float s = 0.f;
#pragma unroll
    for (int c = 0; c < 32; ++c) s += gpart[(size_t)((n << 5) + c) * 5 + j];
    int sp = (e - 1) % 5;
    gram[n * 25 + sp * 5 + j] = s;               // all 32 blocks of image n write
    gram[n * 25 + j * 5 + sp] = s;               // identical values: benign
  }
  __syncthreads();
  if (e >= 2) {
    if (tid == 0) {                              // bordered 6x6 solve, f32 GE w/ pivot
      float A[6][7];
      for (int i = 0; i < 5; ++i)
        for (int j = 0; j < 5; ++j)
          A[i + 1][j + 1] = (i < nact && j < nact)
              ? gram[n * 25 + i * 5 + j] + ((i == j) ? 1e-4f : 0.f)
              : ((i == j) ? 1.f : 0.f);
      A[0][0] = 0.f;
      for (int j = 0; j < 5; ++j) { float aj = (j < nact) ? 1.f : 0.f; A[0][j + 1] = aj; A[j + 1][0] = aj; }
      A[0][6] = 1.f;
      for (int i = 1; i < 6; ++i) A[i][6] = 0.f;
      for (int c = 0; c < 6; ++c) {
        int p = c; float mx = fabsf(A[c][c]);
        for (int r = c + 1; r < 6; ++r) { float v = fabsf(A[r][c]); if (v > mx) { mx = v; p = r; } }
        if (p != c) for (int q = c; q < 7; ++q) { float tmp = A[c][q]; A[c][q] = A[p][q]; A[p][q] = tmp; }
        float piv = A[c][c];
        for (int r = c + 1; r < 6; ++r) {
          float fr = A[r][c] / piv;
          for (int q = c; q < 7; ++q) A[r][q] -= fr * A[c][q];
        }
      }
      float sol[6];
      for (int r = 5; r >= 0; --r) {
        float s = A[r][6];
        for (int q = r + 1; q < 6; ++q) s -= A[r][q] * sol[q];
        sol[r] = s / A[r][r];
      }
      for (int j = 0; j < 5; ++j) alpha_s[j] = sol[j + 1];
    }
  } else if (tid < 5) {
    alpha_s[tid] = (tid == 0) ? 1.f : 0.f;       // e==1: xnew = F0 (e==0 ignores)
  }
  __syncthreads();

  float a0 = 1.f, a1 = 0.f, a2 = 0.f, a3 = 0.f, a4 = 0.f;
  if (e >= 1) { a0 = alpha_s[0]; a1 = alpha_s[1]; a2 = alpha_s[2]; a3 = alpha_s[3]; a4 = alpha_s[4]; }

  // ---- FX own: z = sum_j alpha_j Fh_j, vectorized from packed layout ----
  f32x4 zv[4];                                   // zv[m2*2+nf][rr]
  if (e == 0) {
    const f32x4 cz = {0.0078125f, 0.0078125f, 0.0078125f, 0.0078125f};
    zv[0] = cz; zv[1] = cz; zv[2] = cz; zv[3] = cz;
  } else {
    const float* fb = Fhp + base;
#pragma unroll
    for (int q = 0; q < 4; ++q) zv[q] = a0 * *(const f32x4*)(fb + q * 4);
    if (nact > 1) {
#pragma unroll
      for (int q = 0; q < 4; ++q) zv[q] += a1 * *(const f32x4*)(fb + SLOT + q * 4);
    }
    if (nact > 2) {
#pragma unroll
      for (int q = 0; q < 4; ++q) zv[q] += a2 * *(const f32x4*)(fb + 2 * SLOT + q * 4);
    }
    if (nact > 3) {
#pragma unroll
      for (int q = 0; q < 4; ++q) zv[q] += a3 * *(const f32x4*)(fb + 3 * SLOT + q * 4);
    }
    if (nact > 4) {
#pragma unroll
      for (int q = 0; q < 4; ++q) zv[q] += a4 * *(const f32x4*)(fb + 4 * SLOT + q * 4);
    }
  }

  // ---- own-row staging (tile row 1): mask-merged bf16 scatter ----
#pragma unroll
  for (int m2 = 0; m2 < 2; ++m2)
#pragma unroll
    for (int nf = 0; nf < 2; ++nf)
#pragma unroll
      for (int rr = 0; rr < 4; ++rr) {
        int p = (m2 << 4) + (lhi << 2) + rr;     // x coordinate 0..31
        int ch = (wv << 5) + (nf << 4) + llo;
        int sg = (ch >> 3) ^ (p & 7);
        u16 w;
        if (mk3[32 + p])
          w = xsw[(size_t)(gpix0 + p) * 128 + (sg << 3) + (ch & 7)];
        else
          w = f2bf(zv[(m2 << 1) + nf][rr]);
        *(u16*)(As + 8704 + ((p + 1) << 8) + (sg << 4) + ((ch & 7) << 1)) = w;
      }

  // ---- halo staging: tile rows 0 and 2 (gy = y0-1, y0+1), coalesced short8 ----
#pragma unroll 2
  for (int uu = 0; uu < 4; ++uu) {
    int u = (uu << 8) + tid;                     // 1024 units = 2 rows * 32 px * 16 grp
    int row3 = u >> 9;                           // 0 -> tile row 0, 1 -> tile row 2
    int gy = y0 - 1 + (row3 << 1);
    int idx = u & 511;
    int px = idx >> 4, grp = idx & 15;
    char* dst = As + (row3 << 1) * 8704 + ((px + 1) << 8) + ((grp ^ (px & 7)) << 4);
    short8 w = {0, 0, 0, 0, 0, 0, 0, 0};
    if ((unsigned)gy < 32u) {
      int gpix = (n << 10) + (gy << 5) + px;
      size_t off = (size_t)gpix * 128 + (size_t)((grp ^ (px & 7)) << 3);
      if (mk3[(row3 << 6) + px]) {
        w = *(const short8*)(xsw + off);
      } else if (e == 0) {
#pragma unroll
        for (int i = 0; i < 8; ++i) w[i] = (short)0x3C00;   // bf16(1/128)
      } else {
        f32x4 va, vb;
        short8 h = *(const short8*)(FhH + off);
#pragma unroll
        for (int i = 0; i < 4; ++i) { va[i] = a0 * bf2f((u16)h[i]); vb[i] = a0 * bf2f((u16)h[4 + i]); }
        if (nact > 1) {
          h = *(const short8*)(FhH + SLOT + off);
#pragma unroll
          for (int i = 0; i < 4; ++i) { va[i] += a1 * bf2f((u16)h[i]); vb[i] += a1 * bf2f((u16)h[4 + i]); }
        }
        if (nact > 2) {
          h = *(const short8*)(FhH + 2 * (size_t)SLOT + off);
#pragma unroll
          for (int i = 0; i < 4; ++i) { va[i] += a2 * bf2f((u16)h[i]); vb[i] += a2 * bf2f((u16)h[4 + i]); }
        }
        if (nact > 3) {
          h = *(const short8*)(FhH + 3 * (size_t)SLOT + off);
#pragma unroll
          for (int i = 0; i < 4; ++i) { va[i] += a3 * bf2f((u16)h[i]); vb[i] += a3 * bf2f((u16)h[4 + i]); }
        }
        if (nact > 4) {
          h = *(const short8*)(FhH + 4 * (size_t)SLOT + off);
#pragma unroll
          for (int i = 0; i < 4; ++i) { va[i] += a4 * bf2f((u16)h[i]); vb[i] += a4 * bf2f((u16)h[4 + i]); }
        }
#pragma unroll
        for (int i = 0; i < 4; ++i) { w[i] = (short)f2bf(va[i]); w[4 + i] = (short)f2bf(vb[i]); }
      }
    }
    *(short8*)dst = w;
  }
  if (tid < 96) {                                // zero pads: cols 0 and 33, 3 rows
    int r = tid >> 5, cc = tid & 31;
    int col = (cc < 16) ? 0 : 33, gc = cc & 15;
    f32x4 zz = {0.f, 0.f, 0.f, 0.f};
    *(f32x4*)(As + r * 8704 + (col << 8) + (gc << 4)) = zz;
  }
  __syncthreads();

  // ---- CONV: 144 MFMAs/wave off the LDS tile; B frags from global (L2-hot) ----
  f32x4 acc[2][2];
  {
    const f32x4 z4 = {0.f, 0.f, 0.f, 0.f};
    acc[0][0] = z4; acc[0][1] = z4; acc[1][0] = z4; acc[1][1] = z4;
  }
#pragma unroll
  for (int o = 0; o < 9; ++o) {
    const int dy = o / 3, dx = o % 3;
    short8 bfr[2][4];
#pragma unroll
    for (int nf = 0; nf < 2; ++nf)
#pragma unroll
      for (int kk = 0; kk < 4; ++kk) {
        int ch = (wv << 5) + (nf << 4) + llo;
        bfr[nf][kk] = *(const short8*)(Wb + o * 16384 + ch * 128 + ((kk << 2) + lhi) * 8);
      }
#pragma unroll
    for (int kk = 0; kk < 4; ++kk) {
      const int kg = (kk << 2) + lhi;
#pragma unroll
      for (int m2 = 0; m2 < 2; ++m2) {
        int p = (m2 << 4) + llo;
        int cl = p + dx;
        int sg = kg ^ ((cl - 1) & 7);
        short8 af = *(const short8*)(As + dy * 8704 + (cl << 8) + (sg << 4));
#pragma unroll
        for (int nf = 0; nf < 2; ++nf)
          acc[m2][nf] = __builtin_amdgcn_mfma_f32_16x16x32_bf16(af, bfr[nf][kk], acc[m2][nf], 0, 0, 0);
      }
    }
  }

  // ---- epilogue: damp, channel-softmax(128), fnew, FhH/Fhp/G, partials ----
  const float bc0 = bias[(wv << 5) + llo];
  const float bc1 = bias[(wv << 5) + 16 + llo];
#pragma unroll
  for (int m2 = 0; m2 < 2; ++m2)
#pragma unroll
    for (int rr = 0; rr < 4; ++rr) {
      acc[m2][0][rr] = 0.1f * zv[m2 << 1][rr] + 0.9f * (acc[m2][0][rr] + bc0);
      acc[m2][1][rr] = 0.1f * zv[(m2 << 1) + 1][rr] + 0.9f * (acc[m2][1][rr] + bc1);
    }
#pragma unroll
  for (int m2 = 0; m2 < 2; ++m2)
#pragma unroll
    for (int rr = 0; rr < 4; ++rr) {
      float v = fmaxf(acc[m2][0][rr], acc[m2][1][rr]);
      v = fmaxf(v, __shfl_xor(v, 1)); v = fmaxf(v, __shfl_xor(v, 2));
      v = fmaxf(v, __shfl_xor(v, 4)); v = fmaxf(v, __shfl_xor(v, 8));
      if (llo == 0) rowmax_s[(((m2 << 4) + (lhi << 2) + rr) << 2) + wv] = v;
    }
  __syncthreads();
#pragma unroll
  for (int m2 = 0; m2 < 2; ++m2)
#pragma unroll
    for (int rr = 0; rr < 4; ++rr) {
      int p = (m2 << 4) + (lhi << 2) + rr;
      f32x4 m0 = *(const f32x4*)&rowmax_s[p << 2];
      float M = fmaxf(fmaxf(m0[0], m0[1]), fmaxf(m0[2], m0[3]));
      float e0 = __expf(acc[m2][0][rr] - M);
      float e1 = __expf(acc[m2][1][rr] - M);
      acc[m2][0][rr] = e0; acc[m2][1][rr] = e1;
      float s = e0 + e1;
      s += __shfl_xor(s, 1); s += __shfl_xor(s, 2);
      s += __shfl_xor(s, 4); s += __shfl_xor(s, 8);
      if (llo == 0) rowsum_s[(p << 2) + wv] = s;
    }
  __syncthreads();

  float sd = 0.f, sf = 0.f;
#pragma unroll
  for (int m2 = 0; m2 < 2; ++m2) {
    f32x4 fr0, fr1;
#pragma unroll
    for (int rr = 0; rr < 4; ++rr) {
      int p = (m2 << 4) + (lhi << 2) + rr;
      f32x4 s0 = *(const f32x4*)&rowsum_s[p << 2];
      float S = s0[0] + s0[1] + s0[2] + s0[3];
      float invS = 1.0f / S;
      float f0 = acc[m2][0][rr] * invS;
      float f1 = acc[m2][1][rr] * invS;
      acc[m2][0][rr] = f0; acc[m2][1][rr] = f1;
      fr0[rr] = f0; fr1[rr] = f1;
      float g0 = f0 - zv[m2 << 1][rr];
      float g1 = f1 - zv[(m2 << 1) + 1][rr];
      sd += g0 * g0 + g1 * g1; sf += f0 * f0 + f1 * f1;
      int ch0 = (wv << 5) + llo, ch1 = ch0 + 16;
      size_t rb = (size_t)slot * SLOT + (size_t)(gpix0 + p) * 128;
      FhH[rb + ((((ch0 >> 3) ^ (p & 7)) << 3) | (ch0 & 7))] = f2bf(f0);
      FhH[rb + ((((ch1 >> 3) ^ (p & 7)) << 3) | (ch1 & 7))] = f2bf(f1);
    }
    *(f32x4*)(Fhp + (size_t)slot * SLOT + base + (m2 << 3)) = fr0;
    *(f32x4*)(Fhp + (size_t)slot * SLOT + base + (m2 << 3) + 4) = fr1;
  }
  {
    short8 h0, h1;
#pragma unroll
    for (int m2 = 0; m2 < 2; ++m2)
#pragma unroll
      for (int nf = 0; nf < 2; ++nf)
#pragma unroll
        for (int rr = 0; rr < 4; ++rr) {
          int q = (((m2 << 1) + nf) << 2) + rr;
          u16 gb16 = f2bf(acc[m2][nf][rr] - zv[(m2 << 1) + nf][rr]);
          if (q < 8) h0[q] = (short)gb16; else h1[q - 8] = (short)gb16;
        }
    u16* Gs = Gp + (size_t)slot * SLOT + base;
    *(short8*)(Gs) = h0;
    *(short8*)(Gs + 8) = h1;
    const int jmax = e < 4 ? e : 4;              // valid slots this iteration
    float gacc[5];
#pragma unroll
    for (int j = 0; j < 5; ++j) {
      if (j > jmax) { gacc[j] = 0.f; continue; }
      if (j == slot) {
        float a = 0.f;
#pragma unroll
        for (int m2 = 0; m2 < 2; ++m2)
#pragma unroll
          for (int nf = 0; nf < 2; ++nf)
#pragma unroll
            for (int rr = 0; rr < 4; ++rr) {
              float gd = acc[m2][nf][rr] - zv[(m2 << 1) + nf][rr];
              a += gd * gd;
            }
        gacc[j] = a;
      } else {
        short8 q0 = *(const short8*)(Gp + (size_t)j * SLOT + base);
        short8 q1 = *(const short8*)(Gp + (size_t)j * SLOT + base + 8);
        float a = 0.f;
#pragma unroll
        for (int m2 = 0; m2 < 2; ++m2)
#pragma unroll
          for (int nf = 0; nf < 2; ++nf)
#pragma unroll
            for (int rr = 0; rr < 4; ++rr) {
              int q = (((m2 << 1) + nf) << 2) + rr;
              float gd = acc[m2][nf][rr] - zv[(m2 << 1) + nf][rr];
              float hv = bf2f((u16)(q < 8 ? q0[q] : q1[q - 8]));
              a += gd * hv;
            }
        gacc[j] = a;
      }
    }
    float vals[7] = {gacc[0], gacc[1], gacc[2], gacc[3], gacc[4], sd, sf};
#pragma unroll
    for (int i = 0; i < 7; ++i) {
      float v = vals[i];
#pragma unroll
      for (int off = 1; off < 64; off <<= 1) v += __shfl_xor(v, off);
      if (lane == 0) red[(wv << 3) + i] = v;
    }
  }
  __syncthreads();
  if (tid < 7) {
    float s = 0.f;
#pragma unroll
    for (int w = 0; w < 4; ++w) s += red[(w << 3) + tid];
    if (tid < 5)       gpart[(size_t)lbid * 5 + tid] = s;
    else if (tid == 5) resp[lbid * 2] = s;
    else               resp[lbid * 2 + 1] = s;
  }
}

// ---------------- final: Fhp[last_slot] packed -> d_out NCHW f32
__global__ void __launch_bounds__(256) k_out(const float* __restrict__ Fhp,
    const Ctrl* __restrict__ ctrl, float* __restrict__ out)
{
  __shared__ float T[32 * 132];
  int slot = ctrl->last_slot;
  const int tid = threadIdx.x;
  const int wv = tid >> 6, lane = tid & 63;
  const int lhi = lane >> 4, llo = lane & 15;
  const int lbid = blockIdx.x;                   // 1024 = 32 images * 32 rows
  const int n = lbid >> 5, y0 = lbid & 31;
  const size_t base = (size_t)slot * SLOT + ((size_t)lbid * 256 + tid) * 16;
#pragma unroll
  for (int m2 = 0; m2 < 2; ++m2)
#pragma unroll
    for (int nf = 0; nf < 2; ++nf) {
      f32x4 v = *(const f32x4*)(Fhp + base + (((m2 << 1) + nf) << 2));
#pragma unroll
      for (int rr = 0; rr < 4; ++rr) {
        int p = (m2 << 4) + (lhi << 2) + rr;
        int ch = (wv << 5) + (nf << 4) + llo;
        T[p * 132 + ch] = v[rr];
      }
    }
  __syncthreads();
  int c = tid >> 1, h = tid & 1;
  float* ob = out + (((size_t)(n << 7) + c) << 10) + (y0 << 5) + (h << 4);
#pragma unroll
  for (int i2 = 0; i2 < 4; ++i2) {
    f32x4 v;
#pragma unroll
    for (int i = 0; i < 4; ++i) v[i] = T[((h << 4) + (i2 << 2) + i) * 132 + c];
    *(f32x4*)(ob + (i2 << 2)) = v;
  }
}

extern "C" void kernel_launch(void* const* d_in, const int* in_sizes, int n_in,
                              void* d_out, int out_size, void* d_ws, size_t ws_size,
                              hipStream_t stream) {
  const float* x    = (const float*)d_in[0];   // [32,128,32,32]
  const float* W    = (const float*)d_in[1];   // [128,128,3,3]
  const float* bias = (const float*)d_in[2];   // [128]
  const int*   mask = (const int*)d_in[3];     // [32,1,32,32]
  float* out = (float*)d_out;
  char* ws = (char*)d_ws;

  float* Fhp   = (float*)(ws + 0);             // 83,886,080 (packed f32)
  u16*   FhH   = (u16*)(ws + 83886080);        // 41,943,040 (bf16 NHWC swizzled)
  u16*   Gp    = (u16*)(ws + 125829120);       // 41,943,040 (packed bf16)
  u16*   xsw   = (u16*)(ws + 167772160);       // 8,388,608
  u16*   Wb    = (u16*)(ws + 176160768);       // 294,912
  float* gram  = (float*)(ws + 176455680);     // 3,200
  float* gpart = (float*)(ws + 176458880);     // 20,480
  float* resp  = (float*)(ws + 176479360);     // 8,192
  Ctrl*  ctrl  = (Ctrl*)(ws + 176487552);

  k_prepw<<<576, 256, 0, stream>>>(W, Wb, ctrl);
  k_prepx<<<2048, 256, 0, stream>>>(x, xsw);
  for (int e = 0; e < 50; ++e)
    k_iter<<<1024, 256, 0, stream>>>(e, xsw, mask, Wb, bias,
                                     Fhp, FhH, Gp, gram, gpart, resp, ctrl);
  k_out<<<1024, 256, 0, stream>>>(Fhp, ctrl, out);
  (void)in_sizes; (void)n_in; (void)out_size; (void)ws_size;
}

// Round 10
// 425.895 us; speedup vs baseline: 1.1258x; 1.1258x over previous
//
#include <hip/hip_runtime.h>

// MON forward-backward splitting via Anderson acceleration, MI355X/gfx950.
// R9: R8 geometry (1024 blk x 256 thr, 1-row strips, 27.8KB LDS) with the
//     PROVEN spill-free allocator pin from R7: amdgpu_waves_per_eu(2,4)
//     (budget 128 VGPR -> ~116 used, 4 blocks/CU). R8's waves_per_eu(5) made
//     the backend target 10 waves/SIMD -> 48 VGPR + 28MB spill. Also: halo
//     global loads issue BEFORE own-row LDS scatter (latency overlap).

typedef unsigned short u16;
using short8 = __attribute__((ext_vector_type(8))) short;
using f32x4  = __attribute__((ext_vector_type(4))) float;

#define SLOT 4194304              // elements per history slot (32768 px * 128 ch)

struct Ctrl { int done; int last_slot; };

__device__ __forceinline__ u16 f2bf(float f) {
  unsigned u = __builtin_bit_cast(unsigned, f);
  unsigned r = (u + 0x7FFFu + ((u >> 16) & 1u)) >> 16;   // RNE, finite inputs
  return (u16)r;
}
__device__ __forceinline__ float bf2f(u16 h) {
  unsigned u = ((unsigned)h) << 16;
  return __builtin_bit_cast(float, u);
}

// ---------------- W[cout][cin][ky][kx] f32 -> Wb[o][cout][cin] bf16; ctrl init
__global__ void __launch_bounds__(256) k_prepw(const float* __restrict__ W,
    u16* __restrict__ Wb, Ctrl* ctrl) {
  if (blockIdx.x == 0 && threadIdx.x == 0) { ctrl->done = 0; ctrl->last_slot = 4; }
  int t = blockIdx.x * 256 + threadIdx.x;       // 9*128*128 threads
  int o = t >> 14;
  int rem = t & 16383;
  int cout = rem >> 7, cin = rem & 127;
  float v = W[(size_t)cout * 1152 + (size_t)cin * 9 + o];
  Wb[(size_t)o * 16384 + (size_t)cout * 128 + cin] = f2bf(v);
}

// ---------------- x NCHW f32 -> xsw bf16 swizzled NHWC
__global__ void __launch_bounds__(256) k_prepx(const float* __restrict__ x,
    u16* __restrict__ xsw) {
  int t = blockIdx.x * 256 + threadIdx.x;       // 524288 threads
  int g = t >> 15, p = t & 32767;
  int nb = p >> 10, gp = p & 1023, px = p & 31;
  short8 xv;
#pragma unroll
  for (int u = 0; u < 8; ++u) {
    float v = x[(size_t)nb * 131072 + (size_t)(g * 8 + u) * 1024 + gp];
    xv[u] = (short)f2bf(v);
  }
  *(short8*)(xsw + (size_t)p * 128 + (size_t)((g ^ (px & 7)) << 3)) = xv;
}

// ---------------- one Anderson iteration, fully fused ----------------
// 1024 blocks x 256 threads; lbid = 1-row strip (n = lbid>>5, y0 = lbid&31).
// Wave wv handles 32 px x 32 ch (acc[2][2]); thread owns 16 elems:
// q=(m2*2+nf)*4+rr <-> pixel p=m2*16+lhi*4+rr (x coord), ch=wv*32+nf*16+llo.
// Packed layout: Fhp/Gp elem index = (lbid*256+tid)*16 + q.
__global__ void __launch_bounds__(256)
__attribute__((amdgpu_waves_per_eu(2, 4)))
k_iter(
    const int e,
    const u16* __restrict__ xsw, const int* __restrict__ mask_,
    const u16* __restrict__ Wb, const float* __restrict__ bias,
    float* __restrict__ Fhp, u16* __restrict__ FhH, u16* __restrict__ Gp,
    float* __restrict__ gram, float* __restrict__ gpart,
    float* __restrict__ resp, Ctrl* __restrict__ ctrl)
{
  __shared__ char smem[27776];
  char*  As       = smem;                        // 3 rows * 34 cols * 256B = 26112
  float* rowmax_s = (float*)(smem + 26112);      // [32][4] = 512
  float* rowsum_s = (float*)(smem + 26624);      // 512
  float* red      = (float*)(smem + 27136);      // 4 waves * 8 = 128
  float* alpha_s  = (float*)(smem + 27264);      // 5
  float* res_s    = (float*)(smem + 27284);      // 1
  int*   mk3      = (int*)(smem + 27392);        // 96 (rows y0-1, y0, y0+1)

  if (ctrl->done) return;

  const int tid = threadIdx.x;
  const int wv = tid >> 6, lane = tid & 63;
  const int lhi = lane >> 4, llo = lane & 15;
  const int bhw = blockIdx.x;
  const int lbid = ((bhw & 7) << 7) + (bhw >> 3);    // XCD chunk swizzle (1024=8*128)
  const int n = lbid >> 5, y0 = lbid & 31;
  const int gpix0 = (n << 10) + (y0 << 5);
  const int slot = e % 5;
  const int nact = e < 5 ? e : 5;
  const size_t base = ((size_t)lbid * 256 + tid) * 16;

  // ---- res gate (cond before body e uses res of eval e-1) ----
  if (e >= 3) {
    if (tid < 64) {
      float sd = 0.f, sf = 0.f;
      for (int i = tid; i < 1024; i += 64) { sd += resp[2 * i]; sf += resp[2 * i + 1]; }
#pragma unroll
      for (int off = 1; off < 64; off <<= 1) { sd += __shfl_xor(sd, off); sf += __shfl_xor(sf, off); }
      if (tid == 0) res_s[0] = sqrtf(sd) / (1e-5f + sqrtf(sf));
    }
    __syncthreads();
    if (res_s[0] < 1e-5f) {                      // identical decision in every block
      if (tid == 0) { ctrl->done = 1; ctrl->last_slot = (e - 1) % 5; }
      return;
    }
  }

  // ---- masks (3 rows) + gram fold of slot (e-1)%5 ----
  if (tid < 96) {
    int r = tid >> 5, xx = tid & 31;
    int gy = y0 - 1 + r;
    mk3[tid] = ((unsigned)gy < 32u) ? mask_[(n << 10) + (gy << 5) + xx] : 0;
  }
  if (e >= 1 && tid >= 96 && tid < 101) {
    int j = tid - 96;
    float s = 0.f;
#pragma unroll
    for (int c = 0; c < 32; ++c) s += gpart[(size_t)((n << 5) + c) * 5 + j];
    int sp = (e - 1) % 5;
    gram[n * 25 + sp * 5 + j] = s;               // all 32 blocks of image n write
    gram[n * 25 + j * 5 + sp] = s;               // identical values: benign
  }
  __syncthreads();
  if (e >= 2) {
    if (tid == 0) {                              // bordered 6x6 solve, f32 GE w/ pivot
      float A[6][7];
      for (int i = 0; i < 5; ++i)
        for (int j = 0; j < 5; ++j)
          A[i + 1][j + 1] = (i < nact && j < nact)
              ? gram[n * 25 + i * 5 + j] + ((i == j) ? 1e-4f : 0.f)
              : ((i == j) ? 1.f : 0.f);
      A[0][0] = 0.f;
      for (int j = 0; j < 5; ++j) { float aj = (j < nact) ? 1.f : 0.f; A[0][j + 1] = aj; A[j + 1][0] = aj; }
      A[0][6] = 1.f;
      for (int i = 1; i < 6; ++i) A[i][6] = 0.f;
      for (int c = 0; c < 6; ++c) {
        int p = c; float mx = fabsf(A[c][c]);
        for (int r = c + 1; r < 6; ++r) { float v = fabsf(A[r][c]); if (v > mx) { mx = v; p = r; } }
        if (p != c) for (int q = c; q < 7; ++q) { float tmp = A[c][q]; A[c][q] = A[p][q]; A[p][q] = tmp; }
        float piv = A[c][c];
        for (int r = c + 1; r < 6; ++r) {
          float fr = A[r][c] / piv;
          for (int q = c; q < 7; ++q) A[r][q] -= fr * A[c][q];
        }
      }
      float sol[6];
      for (int r = 5; r >= 0; --r) {
        float s = A[r][6];
        for (int q = r + 1; q < 6; ++q) s -= A[r][q] * sol[q];
        sol[r] = s / A[r][r];
      }
      for (int j = 0; j < 5; ++j) alpha_s[j] = sol[j + 1];
    }
  } else if (tid < 5) {
    alpha_s[tid] = (tid == 0) ? 1.f : 0.f;       // e==1: xnew = F0 (e==0 ignores)
  }
  __syncthreads();

  float a0 = 1.f, a1 = 0.f, a2 = 0.f, a3 = 0.f, a4 = 0.f;
  if (e >= 1) { a0 = alpha_s[0]; a1 = alpha_s[1]; a2 = alpha_s[2]; a3 = alpha_s[3]; a4 = alpha_s[4]; }

  // ---- halo staging FIRST: tile rows 0 and 2 (gy = y0-1, y0+1) — issue the
  //      global loads early; own-row FX below overlaps their latency ----
#pragma unroll
  for (int uu = 0; uu < 4; ++uu) {
    int u = (uu << 8) + tid;                     // 1024 units = 2 rows * 32 px * 16 grp
    int row3 = u >> 9;                           // 0 -> tile row 0, 1 -> tile row 2
    int gy = y0 - 1 + (row3 << 1);
    int idx = u & 511;
    int px = idx >> 4, grp = idx & 15;
    char* dst = As + (row3 << 1) * 8704 + ((px + 1) << 8) + ((grp ^ (px & 7)) << 4);
    short8 w = {0, 0, 0, 0, 0, 0, 0, 0};
    if ((unsigned)gy < 32u) {
      int gpix = (n << 10) + (gy << 5) + px;
      size_t off = (size_t)gpix * 128 + (size_t)((grp ^ (px & 7)) << 3);
      if (mk3[(row3 << 6) + px]) {
        w = *(const short8*)(xsw + off);
      } else if (e == 0) {
#pragma unroll
        for (int i = 0; i < 8; ++i) w[i] = (short)0x3C00;   // bf16(1/128)
      } else {
        f32x4 va, vb;
        short8 h = *(const short8*)(FhH + off);
#pragma unroll
        for (int i = 0; i < 4; ++i) { va[i] = a0 * bf2f((u16)h[i]); vb[i] = a0 * bf2f((u16)h[4 + i]); }
        if (nact > 1) {
          h = *(const short8*)(FhH + SLOT + off);
#pragma unroll
          for (int i = 0; i < 4; ++i) { va[i] += a1 * bf2f((u16)h[i]); vb[i] += a1 * bf2f((u16)h[4 + i]); }
        }
        if (nact > 2) {
          h = *(const short8*)(FhH + 2 * (size_t)SLOT + off);
#pragma unroll
          for (int i = 0; i < 4; ++i) { va[i] += a2 * bf2f((u16)h[i]); vb[i] += a2 * bf2f((u16)h[4 + i]); }
        }
        if (nact > 3) {
          h = *(const short8*)(FhH + 3 * (size_t)SLOT + off);
#pragma unroll
          for (int i = 0; i < 4; ++i) { va[i] += a3 * bf2f((u16)h[i]); vb[i] += a3 * bf2f((u16)h[4 + i]); }
        }
        if (nact > 4) {
          h = *(const short8*)(FhH + 4 * (size_t)SLOT + off);
#pragma unroll
          for (int i = 0; i < 4; ++i) { va[i] += a4 * bf2f((u16)h[i]); vb[i] += a4 * bf2f((u16)h[4 + i]); }
        }
#pragma unroll
        for (int i = 0; i < 4; ++i) { w[i] = (short)f2bf(va[i]); w[4 + i] = (short)f2bf(vb[i]); }
      }
    }
    *(short8*)dst = w;
  }

  // ---- FX own: z = sum_j alpha_j Fh_j, vectorized from packed layout ----
  f32x4 zv[4];                                   // zv[m2*2+nf][rr]
  if (e == 0) {
    const f32x4 cz = {0.0078125f, 0.0078125f, 0.0078125f, 0.0078125f};
    zv[0] = cz; zv[1] = cz; zv[2] = cz; zv[3] = cz;
  } else {
    const float* fb = Fhp + base;
#pragma unroll
    for (int q = 0; q < 4; ++q) zv[q] = a0 * *(const f32x4*)(fb + q * 4);
    if (nact > 1) {
#pragma unroll
      for (int q = 0; q < 4; ++q) zv[q] += a1 * *(const f32x4*)(fb + SLOT + q * 4);
    }
    if (nact > 2) {
#pragma unroll
      for (int q = 0; q < 4; ++q) zv[q] += a2 * *(const f32x4*)(fb + 2 * SLOT + q * 4);
    }
    if (nact > 3) {
#pragma unroll
      for (int q = 0; q < 4; ++q) zv[q] += a3 * *(const f32x4*)(fb + 3 * SLOT + q * 4);
    }
    if (nact > 4) {
#pragma unroll
      for (int q = 0; q < 4; ++q) zv[q] += a4 * *(const f32x4*)(fb + 4 * SLOT + q * 4);
    }
  }

  // ---- own-row staging (tile row 1): mask-merged bf16 scatter ----
#pragma unroll
  for (int m2 = 0; m2 < 2; ++m2)
#pragma unroll
    for (int nf = 0; nf < 2; ++nf)
#pragma unroll
      for (int rr = 0; rr < 4; ++rr) {
        int p = (m2 << 4) + (lhi << 2) + rr;     // x coordinate 0..31
        int ch = (wv << 5) + (nf << 4) + llo;
        int sg = (ch >> 3) ^ (p & 7);
        u16 w;
        if (mk3[32 + p])
          w = xsw[(size_t)(gpix0 + p) * 128 + (sg << 3) + (ch & 7)];
        else
          w = f2bf(zv[(m2 << 1) + nf][rr]);
        *(u16*)(As + 8704 + ((p + 1) << 8) + (sg << 4) + ((ch & 7) << 1)) = w;
      }

  if (tid < 96) {                                // zero pads: cols 0 and 33, 3 rows
    int r = tid >> 5, cc = tid & 31;
    int col = (cc < 16) ? 0 : 33, gc = cc & 15;
    f32x4 zz = {0.f, 0.f, 0.f, 0.f};
    *(f32x4*)(As + r * 8704 + (col << 8) + (gc << 4)) = zz;
  }
  __syncthreads();

  // ---- CONV: 144 MFMAs/wave off the LDS tile; B frags from global (L2-hot) ----
  f32x4 acc[2][2];
  {
    const f32x4 z4 = {0.f, 0.f, 0.f, 0.f};
    acc[0][0] = z4; acc[0][1] = z4; acc[1][0] = z4; acc[1][1] = z4;
  }
#pragma unroll
  for (int o = 0; o < 9; ++o) {
    const int dy = o / 3, dx = o % 3;
    short8 bfr[2][4];
#pragma unroll
    for (int nf = 0; nf < 2; ++nf)
#pragma unroll
      for (int kk = 0; kk < 4; ++kk) {
        int ch = (wv << 5) + (nf << 4) + llo;
        bfr[nf][kk] = *(const short8*)(Wb + o * 16384 + ch * 128 + ((kk << 2) + lhi) * 8);
      }
#pragma unroll
    for (int kk = 0; kk < 4; ++kk) {
      const int kg = (kk << 2) + lhi;
#pragma unroll
      for (int m2 = 0; m2 < 2; ++m2) {
        int p = (m2 << 4) + llo;
        int cl = p + dx;
        int sg = kg ^ ((cl - 1) & 7);
        short8 af = *(const short8*)(As + dy * 8704 + (cl << 8) + (sg << 4));
#pragma unroll
        for (int nf = 0; nf < 2; ++nf)
          acc[m2][nf] = __builtin_amdgcn_mfma_f32_16x16x32_bf16(af, bfr[nf][kk], acc[m2][nf], 0, 0, 0);
      }
    }
  }

  // ---- epilogue: damp, channel-softmax(128), fnew, FhH/Fhp/G, partials ----
  const float bc0 = bias[(wv << 5) + llo];
  const float bc1 = bias[(wv << 5) + 16 + llo];
#pragma unroll
  for (int m2 = 0; m2 < 2; ++m2)
#pragma unroll
    for (int rr = 0; rr < 4; ++rr) {
      acc[m2][0][rr] = 0.1f * zv[m2 << 1][rr] + 0.9f * (acc[m2][0][rr] + bc0);
      acc[m2][1][rr] = 0.1f * zv[(m2 << 1) + 1][rr] + 0.9f * (acc[m2][1][rr] + bc1);
    }
#pragma unroll
  for (int m2 = 0; m2 < 2; ++m2)
#pragma unroll
    for (int rr = 0; rr < 4; ++rr) {
      float v = fmaxf(acc[m2][0][rr], acc[m2][1][rr]);
      v = fmaxf(v, __shfl_xor(v, 1)); v = fmaxf(v, __shfl_xor(v, 2));
      v = fmaxf(v, __shfl_xor(v, 4)); v = fmaxf(v, __shfl_xor(v, 8));
      if (llo == 0) rowmax_s[(((m2 << 4) + (lhi << 2) + rr) << 2) + wv] = v;
    }
  __syncthreads();
#pragma unroll
  for (int m2 = 0; m2 < 2; ++m2)
#pragma unroll
    for (int rr = 0; rr < 4; ++rr) {
      int p = (m2 << 4) + (lhi << 2) + rr;
      f32x4 m0 = *(const f32x4*)&rowmax_s[p << 2];
      float M = fmaxf(fmaxf(m0[0], m0[1]), fmaxf(m0[2], m0[3]));
      float e0 = __expf(acc[m2][0][rr] - M);
      float e1 = __expf(acc[m2][1][rr] - M);
      acc[m2][0][rr] = e0; acc[m2][1][rr] = e1;
      float s = e0 + e1;
      s += __shfl_xor(s, 1); s += __shfl_xor(s, 2);
      s += __shfl_xor(s, 4); s += __shfl_xor(s, 8);
      if (llo == 0) rowsum_s[(p << 2) + wv] = s;
    }
  __syncthreads();

  float sd = 0.f, sf = 0.f;
#pragma unroll
  for (int m2 = 0; m2 < 2; ++m2) {
    f32x4 fr0, fr1;
#pragma unroll
    for (int rr = 0; rr < 4; ++rr) {
      int p = (m2 << 4) + (lhi << 2) + rr;
      f32x4 s0 = *(const f32x4*)&rowsum_s[p << 2];
      float S = s0[0] + s0[1] + s0[2] + s0[3];
      float invS = 1.0f / S;
      float f0 = acc[m2][0][rr] * invS;
      float f1 = acc[m2][1][rr] * invS;
      acc[m2][0][rr] = f0; acc[m2][1][rr] = f1;
      fr0[rr] = f0; fr1[rr] = f1;
      float g0 = f0 - zv[m2 << 1][rr];
      float g1 = f1 - zv[(m2 << 1) + 1][rr];
      sd += g0 * g0 + g1 * g1; sf += f0 * f0 + f1 * f1;
      int ch0 = (wv << 5) + llo, ch1 = ch0 + 16;
      size_t rb = (size_t)slot * SLOT + (size_t)(gpix0 + p) * 128;
      FhH[rb + ((((ch0 >> 3) ^ (p & 7)) << 3) | (ch0 & 7))] = f2bf(f0);
      FhH[rb + ((((ch1 >> 3) ^ (p & 7)) << 3) | (ch1 & 7))] = f2bf(f1);
    }
    *(f32x4*)(Fhp + (size_t)slot * SLOT + base + (m2 << 3)) = fr0;
    *(f32x4*)(Fhp + (size_t)slot * SLOT + base + (m2 << 3) + 4) = fr1;
  }
  {
    short8 h0, h1;
#pragma unroll
    for (int m2 = 0; m2 < 2; ++m2)
#pragma unroll
      for (int nf = 0; nf < 2; ++nf)
#pragma unroll
        for (int rr = 0; rr < 4; ++rr) {
          int q = (((m2 << 1) + nf) << 2) + rr;
          u16 gb16 = f2bf(acc[m2][nf][rr] - zv[(m2 << 1) + nf][rr]);
          if (q < 8) h0[q] = (short)gb16; else h1[q - 8] = (short)gb16;
        }
    u16* Gs = Gp + (size_t)slot * SLOT + base;
    *(short8*)(Gs) = h0;
    *(short8*)(Gs + 8) = h1;
    const int jmax = e < 4 ? e : 4;              // valid slots this iteration
    float gacc[5];
#pragma unroll
    for (int j = 0; j < 5; ++j) {
      if (j > jmax) { gacc[j] = 0.f; continue; }
      if (j == slot) {
        float a = 0.f;
#pragma unroll
        for (int m2 = 0; m2 < 2; ++m2)
#pragma unroll
          for (int nf = 0; nf < 2; ++nf)
#pragma unroll
            for (int rr = 0; rr < 4; ++rr) {
              float gd = acc[m2][nf][rr] - zv[(m2 << 1) + nf][rr];
              a += gd * gd;
            }
        gacc[j] = a;
      } else {
        short8 q0 = *(const short8*)(Gp + (size_t)j * SLOT + base);
        short8 q1 = *(const short8*)(Gp + (size_t)j * SLOT + base + 8);
        float a = 0.f;
#pragma unroll
        for (int m2 = 0; m2 < 2; ++m2)
#pragma unroll
          for (int nf = 0; nf < 2; ++nf)
#pragma unroll
            for (int rr = 0; rr < 4; ++rr) {
              int q = (((m2 << 1) + nf) << 2) + rr;
              float gd = acc[m2][nf][rr] - zv[(m2 << 1) + nf][rr];
              float hv = bf2f((u16)(q < 8 ? q0[q] : q1[q - 8]));
              a += gd * hv;
            }
        gacc[j] = a;
      }
    }
    float vals[7] = {gacc[0], gacc[1], gacc[2], gacc[3], gacc[4], sd, sf};
#pragma unroll
    for (int i = 0; i < 7; ++i) {
      float v = vals[i];
#pragma unroll
      for (int off = 1; off < 64; off <<= 1) v += __shfl_xor(v, off);
      if (lane == 0) red[(wv << 3) + i] = v;
    }
  }
  __syncthreads();
  if (tid < 7) {
    float s = 0.f;
#pragma unroll
    for (int w = 0; w < 4; ++w) s += red[(w << 3) + tid];
    if (tid < 5)       gpart[(size_t)lbid * 5 + tid] = s;
    else if (tid == 5) resp[lbid * 2] = s;
    else               resp[lbid * 2 + 1] = s;
  }
}

// ---------------- final: Fhp[last_slot] packed -> d_out NCHW f32
__global__ void __launch_bounds__(256) k_out(const float* __restrict__ Fhp,
    const Ctrl* __restrict__ ctrl, float* __restrict__ out)
{
  __shared__ float T[32 * 132];
  int slot = ctrl->last_slot;
  const int tid = threadIdx.x;
  const int wv = tid >> 6, lane = tid & 63;
  const int lhi = lane >> 4, llo = lane & 15;
  const int lbid = blockIdx.x;                   // 1024 = 32 images * 32 rows
  const int n = lbid >> 5, y0 = lbid & 31;
  const size_t base = (size_t)slot * SLOT + ((size_t)lbid * 256 + tid) * 16;
#pragma unroll
  for (int m2 = 0; m2 < 2; ++m2)
#pragma unroll
    for (int nf = 0; nf < 2; ++nf) {
      f32x4 v = *(const f32x4*)(Fhp + base + (((m2 << 1) + nf) << 2));
#pragma unroll
      for (int rr = 0; rr < 4; ++rr) {
        int p = (m2 << 4) + (lhi << 2) + rr;
        int ch = (wv << 5) + (nf << 4) + llo;
        T[p * 132 + ch] = v[rr];
      }
    }
  __syncthreads();
  int c = tid >> 1, h = tid & 1;
  float* ob = out + (((size_t)(n << 7) + c) << 10) + (y0 << 5) + (h << 4);
#pragma unroll
  for (int i2 = 0; i2 < 4; ++i2) {
    f32x4 v;
#pragma unroll
    for (int i = 0; i < 4; ++i) v[i] = T[((h << 4) + (i2 << 2) + i) * 132 + c];
    *(f32x4*)(ob + (i2 << 2)) = v;
  }
}

extern "C" void kernel_launch(void* const* d_in, const int* in_sizes, int n_in,
                              void* d_out, int out_size, void* d_ws, size_t ws_size,
                              hipStream_t stream) {
  const float* x    = (const float*)d_in[0];   // [32,128,32,32]
  const float* W    = (const float*)d_in[1];   // [128,128,3,3]
  const float* bias = (const float*)d_in[2];   // [128]
  const int*   mask = (const int*)d_in[3];     // [32,1,32,32]
  float* out = (float*)d_out;
  char* ws = (char*)d_ws;

  float* Fhp   = (float*)(ws + 0);             // 83,886,080 (packed f32)
  u16*   FhH   = (u16*)(ws + 83886080);        // 41,943,040 (bf16 NHWC swizzled)
  u16*   Gp    = (u16*)(ws + 125829120);       // 41,943,040 (packed bf16)
  u16*   xsw   = (u16*)(ws + 167772160);       // 8,388,608
  u16*   Wb    = (u16*)(ws + 176160768);       // 294,912
  float* gram  = (float*)(ws + 176455680);     // 3,200
  float* gpart = (float*)(ws + 176458880);     // 20,480
  float* resp  = (float*)(ws + 176479360);     // 8,192
  Ctrl*  ctrl  = (Ctrl*)(ws + 176487552);

  k_prepw<<<576, 256, 0, stream>>>(W, Wb, ctrl);
  k_prepx<<<2048, 256, 0, stream>>>(x, xsw);
  for (int e = 0; e < 50; ++e)
    k_iter<<<1024, 256, 0, stream>>>(e, xsw, mask, Wb, bias,
                                     Fhp, FhH, Gp, gram, gpart, resp, ctrl);
  k_out<<<1024, 256, 0, stream>>>(Fhp, ctrl, out);
  (void)in_sizes; (void)n_in; (void)out_size; (void)ws_size;
}

// Round 11
// 422.277 us; speedup vs baseline: 1.1355x; 1.0086x over previous
//
#include <hip/hip_runtime.h>

// MON forward-backward splitting via Anderson acceleration, MI355X/gfx950.
// R10: MLP fix. R9 showed VGPR=64 spill-free but load-serialized (1.18 TB/s,
//      87us/iter, all pipes idle => outstanding-request bound). This round:
//      amdgpu_waves_per_eu(4,4) (budget 128 VGPR, occupancy target 4/EU =
//      what the 4-blocks/CU grid gives anyway) + source-level load batching:
//      FX-own loads all 5 slots into regs before combining, halo loads 5
//      slot payloads per unit before combining, gram tail batches Gp reads.

typedef unsigned short u16;
using short8 = __attribute__((ext_vector_type(8))) short;
using f32x4  = __attribute__((ext_vector_type(4))) float;

#define SLOT 4194304              // elements per history slot (32768 px * 128 ch)

struct Ctrl { int done; int last_slot; };

__device__ __forceinline__ u16 f2bf(float f) {
  unsigned u = __builtin_bit_cast(unsigned, f);
  unsigned r = (u + 0x7FFFu + ((u >> 16) & 1u)) >> 16;   // RNE, finite inputs
  return (u16)r;
}
__device__ __forceinline__ float bf2f(u16 h) {
  unsigned u = ((unsigned)h) << 16;
  return __builtin_bit_cast(float, u);
}

// ---------------- W[cout][cin][ky][kx] f32 -> Wb[o][cout][cin] bf16; ctrl init
__global__ void __launch_bounds__(256) k_prepw(const float* __restrict__ W,
    u16* __restrict__ Wb, Ctrl* ctrl) {
  if (blockIdx.x == 0 && threadIdx.x == 0) { ctrl->done = 0; ctrl->last_slot = 4; }
  int t = blockIdx.x * 256 + threadIdx.x;       // 9*128*128 threads
  int o = t >> 14;
  int rem = t & 16383;
  int cout = rem >> 7, cin = rem & 127;
  float v = W[(size_t)cout * 1152 + (size_t)cin * 9 + o];
  Wb[(size_t)o * 16384 + (size_t)cout * 128 + cin] = f2bf(v);
}

// ---------------- x NCHW f32 -> xsw bf16 swizzled NHWC
__global__ void __launch_bounds__(256) k_prepx(const float* __restrict__ x,
    u16* __restrict__ xsw) {
  int t = blockIdx.x * 256 + threadIdx.x;       // 524288 threads
  int g = t >> 15, p = t & 32767;
  int nb = p >> 10, gp = p & 1023, px = p & 31;
  short8 xv;
#pragma unroll
  for (int u = 0; u < 8; ++u) {
    float v = x[(size_t)nb * 131072 + (size_t)(g * 8 + u) * 1024 + gp];
    xv[u] = (short)f2bf(v);
  }
  *(short8*)(xsw + (size_t)p * 128 + (size_t)((g ^ (px & 7)) << 3)) = xv;
}

// ---------------- one Anderson iteration, fully fused ----------------
// 1024 blocks x 256 threads; lbid = 1-row strip (n = lbid>>5, y0 = lbid&31).
// Wave wv handles 32 px x 32 ch (acc[2][2]); thread owns 16 elems:
// q=(m2*2+nf)*4+rr <-> pixel p=m2*16+lhi*4+rr (x coord), ch=wv*32+nf*16+llo.
// Packed layout: Fhp/Gp elem index = (lbid*256+tid)*16 + q.
__global__ void __launch_bounds__(256)
__attribute__((amdgpu_waves_per_eu(4, 4)))
k_iter(
    const int e,
    const u16* __restrict__ xsw, const int* __restrict__ mask_,
    const u16* __restrict__ Wb, const float* __restrict__ bias,
    float* __restrict__ Fhp, u16* __restrict__ FhH, u16* __restrict__ Gp,
    float* __restrict__ gram, float* __restrict__ gpart,
    float* __restrict__ resp, Ctrl* __restrict__ ctrl)
{
  __shared__ char smem[27776];
  char*  As       = smem;                        // 3 rows * 34 cols * 256B = 26112
  float* rowmax_s = (float*)(smem + 26112);      // [32][4] = 512
  float* rowsum_s = (float*)(smem + 26624);      // 512
  float* red      = (float*)(smem + 27136);      // 4 waves * 8 = 128
  float* alpha_s  = (float*)(smem + 27264);      // 5
  float* res_s    = (float*)(smem + 27284);      // 1
  int*   mk3      = (int*)(smem + 27392);        // 96 (rows y0-1, y0, y0+1)

  if (ctrl->done) return;

  const int tid = threadIdx.x;
  const int wv = tid >> 6, lane = tid & 63;
  const int lhi = lane >> 4, llo = lane & 15;
  const int bhw = blockIdx.x;
  const int lbid = ((bhw & 7) << 7) + (bhw >> 3);    // XCD chunk swizzle (1024=8*128)
  const int n = lbid >> 5, y0 = lbid & 31;
  const int gpix0 = (n << 10) + (y0 << 5);
  const int slot = e % 5;
  const int nact = e < 5 ? e : 5;
  const size_t base = ((size_t)lbid * 256 + tid) * 16;

  // ---- res gate (cond before body e uses res of eval e-1) ----
  if (e >= 3) {
    if (tid < 64) {
      float sd = 0.f, sf = 0.f;
      for (int i = tid; i < 1024; i += 64) { sd += resp[2 * i]; sf += resp[2 * i + 1]; }
#pragma unroll
      for (int off = 1; off < 64; off <<= 1) { sd += __shfl_xor(sd, off); sf += __shfl_xor(sf, off); }
      if (tid == 0) res_s[0] = sqrtf(sd) / (1e-5f + sqrtf(sf));
    }
    __syncthreads();
    if (res_s[0] < 1e-5f) {                      // identical decision in every block
      if (tid == 0) { ctrl->done = 1; ctrl->last_slot = (e - 1) % 5; }
      return;
    }
  }

  // ---- masks (3 rows) + gram fold of slot (e-1)%5 ----
  if (tid < 96) {
    int r = tid >> 5, xx = tid & 31;
    int gy = y0 - 1 + r;
    mk3[tid] = ((unsigned)gy < 32u) ? mask_[(n << 10) + (gy << 5) + xx] : 0;
  }
  if (e >= 1 && tid >= 96 && tid < 101) {
    int j = tid - 96;
    float s = 0.f;
#pragma unroll
    for (int c = 0; c < 32; ++c) s += gpart[(size_t)((n << 5) + c) * 5 + j];
    int sp = (e - 1) % 5;
    gram[n * 25 + sp * 5 + j] = s;               // all 32 blocks of image n write
    gram[n * 25 + j * 5 + sp] = s;               // identical values: benign
  }
  __syncthreads();
  if (e >= 2) {
    if (tid == 0) {                              // bordered 6x6 solve, f32 GE w/ pivot
      float A[6][7];
      for (int i = 0; i < 5; ++i)
        for (int j = 0; j < 5; ++j)
          A[i + 1][j + 1] = (i < nact && j < nact)
              ? gram[n * 25 + i * 5 + j] + ((i == j) ? 1e-4f : 0.f)
              : ((i == j) ? 1.f : 0.f);
      A[0][0] = 0.f;
      for (int j = 0; j < 5; ++j) { float aj = (j < nact) ? 1.f : 0.f; A[0][j + 1] = aj; A[j + 1][0] = aj; }
      A[0][6] = 1.f;
      for (int i = 1; i < 6; ++i) A[i][6] = 0.f;
      for (int c = 0; c < 6; ++c) {
        int p = c; float mx = fabsf(A[c][c]);
        for (int r = c + 1; r < 6; ++r) { float v = fabsf(A[r][c]); if (v > mx) { mx = v; p = r; } }
        if (p != c) for (int q = c; q < 7; ++q) { float tmp = A[c][q]; A[c][q] = A[p][q]; A[p][q] = tmp; }
        float piv = A[c][c];
        for (int r = c + 1; r < 6; ++r) {
          float fr = A[r][c] / piv;
          for (int q = c; q < 7; ++q) A[r][q] -= fr * A[c][q];
        }
      }
      float sol[6];
      for (int r = 5; r >= 0; --r) {
        float s = A[r][6];
        for (int q = r + 1; q < 6; ++q) s -= A[r][q] * sol[q];
        sol[r] = s / A[r][r];
      }
      for (int j = 0; j < 5; ++j) alpha_s[j] = sol[j + 1];
    }
  } else if (tid < 5) {
    alpha_s[tid] = (tid == 0) ? 1.f : 0.f;       // e==1: xnew = F0 (e==0 ignores)
  }
  __syncthreads();

  float a0 = 1.f, a1 = 0.f, a2 = 0.f, a3 = 0.f, a4 = 0.f;
  if (e >= 1) { a0 = alpha_s[0]; a1 = alpha_s[1]; a2 = alpha_s[2]; a3 = alpha_s[3]; a4 = alpha_s[4]; }

  // ---- halo staging: tile rows 0 and 2 (gy = y0-1, y0+1). Batched: each
  //      unit issues its 5 slot loads back-to-back, THEN combines. ----
#pragma unroll
  for (int uu = 0; uu < 4; ++uu) {
    int u = (uu << 8) + tid;                     // 1024 units = 2 rows * 32 px * 16 grp
    int row3 = u >> 9;                           // 0 -> tile row 0, 1 -> tile row 2
    int gy = y0 - 1 + (row3 << 1);
    int idx = u & 511;
    int px = idx >> 4, grp = idx & 15;
    char* dst = As + (row3 << 1) * 8704 + ((px + 1) << 8) + ((grp ^ (px & 7)) << 4);
    short8 w = {0, 0, 0, 0, 0, 0, 0, 0};
    if ((unsigned)gy < 32u) {
      int gpix = (n << 10) + (gy << 5) + px;
      size_t off = (size_t)gpix * 128 + (size_t)((grp ^ (px & 7)) << 3);
      if (mk3[(row3 << 6) + px]) {
        w = *(const short8*)(xsw + off);
      } else if (e == 0) {
#pragma unroll
        for (int i = 0; i < 8; ++i) w[i] = (short)0x3C00;   // bf16(1/128)
      } else {
        short8 h0, h1, h2, h3, h4;               // batched issue: 5 loads in flight
        h0 = *(const short8*)(FhH + off);
        if (nact > 1) h1 = *(const short8*)(FhH + SLOT + off);
        if (nact > 2) h2 = *(const short8*)(FhH + 2 * (size_t)SLOT + off);
        if (nact > 3) h3 = *(const short8*)(FhH + 3 * (size_t)SLOT + off);
        if (nact > 4) h4 = *(const short8*)(FhH + 4 * (size_t)SLOT + off);
        f32x4 va, vb;
#pragma unroll
        for (int i = 0; i < 4; ++i) { va[i] = a0 * bf2f((u16)h0[i]); vb[i] = a0 * bf2f((u16)h0[4 + i]); }
        if (nact > 1) {
#pragma unroll
          for (int i = 0; i < 4; ++i) { va[i] += a1 * bf2f((u16)h1[i]); vb[i] += a1 * bf2f((u16)h1[4 + i]); }
        }
        if (nact > 2) {
#pragma unroll
          for (int i = 0; i < 4; ++i) { va[i] += a2 * bf2f((u16)h2[i]); vb[i] += a2 * bf2f((u16)h2[4 + i]); }
        }
        if (nact > 3) {
#pragma unroll
          for (int i = 0; i < 4; ++i) { va[i] += a3 * bf2f((u16)h3[i]); vb[i] += a3 * bf2f((u16)h3[4 + i]); }
        }
        if (nact > 4) {
#pragma unroll
          for (int i = 0; i < 4; ++i) { va[i] += a4 * bf2f((u16)h4[i]); vb[i] += a4 * bf2f((u16)h4[4 + i]); }
        }
#pragma unroll
        for (int i = 0; i < 4; ++i) { w[i] = (short)f2bf(va[i]); w[4 + i] = (short)f2bf(vb[i]); }
      }
    }
    *(short8*)dst = w;
  }

  // ---- FX own: batched — load all 5 slots into regs, then combine ----
  f32x4 zv[4];                                   // zv[m2*2+nf][rr]
  if (e == 0) {
    const f32x4 cz = {0.0078125f, 0.0078125f, 0.0078125f, 0.0078125f};
    zv[0] = cz; zv[1] = cz; zv[2] = cz; zv[3] = cz;
  } else {
    const float* fb = Fhp + base;
    f32x4 t0[4], t1[4], t2[4], t3[4], t4[4];     // up to 80 VGPRs of payload in flight
#pragma unroll
    for (int q = 0; q < 4; ++q) t0[q] = *(const f32x4*)(fb + q * 4);
    if (nact > 1) {
#pragma unroll
      for (int q = 0; q < 4; ++q) t1[q] = *(const f32x4*)(fb + SLOT + q * 4);
    }
    if (nact > 2) {
#pragma unroll
      for (int q = 0; q < 4; ++q) t2[q] = *(const f32x4*)(fb + 2 * SLOT + q * 4);
    }
    if (nact > 3) {
#pragma unroll
      for (int q = 0; q < 4; ++q) t3[q] = *(const f32x4*)(fb + 3 * SLOT + q * 4);
    }
    if (nact > 4) {
#pragma unroll
      for (int q = 0; q < 4; ++q) t4[q] = *(const f32x4*)(fb + 4 * SLOT + q * 4);
    }
#pragma unroll
    for (int q = 0; q < 4; ++q) zv[q] = a0 * t0[q];
    if (nact > 1) {
#pragma unroll
      for (int q = 0; q < 4; ++q) zv[q] += a1 * t1[q];
    }
    if (nact > 2) {
#pragma unroll
      for (int q = 0; q < 4; ++q) zv[q] += a2 * t2[q];
    }
    if (nact > 3) {
#pragma unroll
      for (int q = 0; q < 4; ++q) zv[q] += a3 * t3[q];
    }
    if (nact > 4) {
#pragma unroll
      for (int q = 0; q < 4; ++q) zv[q] += a4 * t4[q];
    }
  }

  // ---- own-row staging (tile row 1): mask-merged bf16 scatter ----
#pragma unroll
  for (int m2 = 0; m2 < 2; ++m2)
#pragma unroll
    for (int nf = 0; nf < 2; ++nf)
#pragma unroll
      for (int rr = 0; rr < 4; ++rr) {
        int p = (m2 << 4) + (lhi << 2) + rr;     // x coordinate 0..31
        int ch = (wv << 5) + (nf << 4) + llo;
        int sg = (ch >> 3) ^ (p & 7);
        u16 w;
        if (mk3[32 + p])
          w = xsw[(size_t)(gpix0 + p) * 128 + (sg << 3) + (ch & 7)];
        else
          w = f2bf(zv[(m2 << 1) + nf][rr]);
        *(u16*)(As + 8704 + ((p + 1) << 8) + (sg << 4) + ((ch & 7) << 1)) = w;
      }

  if (tid < 96) {                                // zero pads: cols 0 and 33, 3 rows
    int r = tid >> 5, cc = tid & 31;
    int col = (cc < 16) ? 0 : 33, gc = cc & 15;
    f32x4 zz = {0.f, 0.f, 0.f, 0.f};
    *(f32x4*)(As + r * 8704 + (col << 8) + (gc << 4)) = zz;
  }
  __syncthreads();

  // ---- CONV: 144 MFMAs/wave off the LDS tile; B frags from global (L2-hot) ----
  f32x4 acc[2][2];
  {
    const f32x4 z4 = {0.f, 0.f, 0.f, 0.f};
    acc[0][0] = z4; acc[0][1] = z4; acc[1][0] = z4; acc[1][1] = z4;
  }
#pragma unroll
  for (int o = 0; o < 9; ++o) {
    const int dy = o / 3, dx = o % 3;
    short8 bfr[2][4];
#pragma unroll
    for (int nf = 0; nf < 2; ++nf)
#pragma unroll
      for (int kk = 0; kk < 4; ++kk) {
        int ch = (wv << 5) + (nf << 4) + llo;
        bfr[nf][kk] = *(const short8*)(Wb + o * 16384 + ch * 128 + ((kk << 2) + lhi) * 8);
      }
#pragma unroll
    for (int kk = 0; kk < 4; ++kk) {
      const int kg = (kk << 2) + lhi;
#pragma unroll
      for (int m2 = 0; m2 < 2; ++m2) {
        int p = (m2 << 4) + llo;
        int cl = p + dx;
        int sg = kg ^ ((cl - 1) & 7);
        short8 af = *(const short8*)(As + dy * 8704 + (cl << 8) + (sg << 4));
#pragma unroll
        for (int nf = 0; nf < 2; ++nf)
          acc[m2][nf] = __builtin_amdgcn_mfma_f32_16x16x32_bf16(af, bfr[nf][kk], acc[m2][nf], 0, 0, 0);
      }
    }
  }

  // ---- epilogue: damp, channel-softmax(128), fnew, FhH/Fhp/G, partials ----
  const float bc0 = bias[(wv << 5) + llo];
  const float bc1 = bias[(wv << 5) + 16 + llo];
#pragma unroll
  for (int m2 = 0; m2 < 2; ++m2)
#pragma unroll
    for (int rr = 0; rr < 4; ++rr) {
      acc[m2][0][rr] = 0.1f * zv[m2 << 1][rr] + 0.9f * (acc[m2][0][rr] + bc0);
      acc[m2][1][rr] = 0.1f * zv[(m2 << 1) + 1][rr] + 0.9f * (acc[m2][1][rr] + bc1);
    }
#pragma unroll
  for (int m2 = 0; m2 < 2; ++m2)
#pragma unroll
    for (int rr = 0; rr < 4; ++rr) {
      float v = fmaxf(acc[m2][0][rr], acc[m2][1][rr]);
      v = fmaxf(v, __shfl_xor(v, 1)); v = fmaxf(v, __shfl_xor(v, 2));
      v = fmaxf(v, __shfl_xor(v, 4)); v = fmaxf(v, __shfl_xor(v, 8));
      if (llo == 0) rowmax_s[(((m2 << 4) + (lhi << 2) + rr) << 2) + wv] = v;
    }
  __syncthreads();
#pragma unroll
  for (int m2 = 0; m2 < 2; ++m2)
#pragma unroll
    for (int rr = 0; rr < 4; ++rr) {
      int p = (m2 << 4) + (lhi << 2) + rr;
      f32x4 m0 = *(const f32x4*)&rowmax_s[p << 2];
      float M = fmaxf(fmaxf(m0[0], m0[1]), fmaxf(m0[2], m0[3]));
      float e0 = __expf(acc[m2][0][rr] - M);
      float e1 = __expf(acc[m2][1][rr] - M);
      acc[m2][0][rr] = e0; acc[m2][1][rr] = e1;
      float s = e0 + e1;
      s += __shfl_xor(s, 1); s += __shfl_xor(s, 2);
      s += __shfl_xor(s, 4); s += __shfl_xor(s, 8);
      if (llo == 0) rowsum_s[(p << 2) + wv] = s;
    }
  __syncthreads();

  float sd = 0.f, sf = 0.f;
#pragma unroll
  for (int m2 = 0; m2 < 2; ++m2) {
    f32x4 fr0, fr1;
#pragma unroll
    for (int rr = 0; rr < 4; ++rr) {
      int p = (m2 << 4) + (lhi << 2) + rr;
      f32x4 s0 = *(const f32x4*)&rowsum_s[p << 2];
      float S = s0[0] + s0[1] + s0[2] + s0[3];
      float invS = 1.0f / S;
      float f0 = acc[m2][0][rr] * invS;
      float f1 = acc[m2][1][rr] * invS;
      acc[m2][0][rr] = f0; acc[m2][1][rr] = f1;
      fr0[rr] = f0; fr1[rr] = f1;
      float g0 = f0 - zv[m2 << 1][rr];
      float g1 = f1 - zv[(m2 << 1) + 1][rr];
      sd += g0 * g0 + g1 * g1; sf += f0 * f0 + f1 * f1;
      int ch0 = (wv << 5) + llo, ch1 = ch0 + 16;
      size_t rb = (size_t)slot * SLOT + (size_t)(gpix0 + p) * 128;
      FhH[rb + ((((ch0 >> 3) ^ (p & 7)) << 3) | (ch0 & 7))] = f2bf(f0);
      FhH[rb + ((((ch1 >> 3) ^ (p & 7)) << 3) | (ch1 & 7))] = f2bf(f1);
    }
    *(f32x4*)(Fhp + (size_t)slot * SLOT + base + (m2 << 3)) = fr0;
    *(f32x4*)(Fhp + (size_t)slot * SLOT + base + (m2 << 3) + 4) = fr1;
  }
  {
    short8 h0, h1;
#pragma unroll
    for (int m2 = 0; m2 < 2; ++m2)
#pragma unroll
      for (int nf = 0; nf < 2; ++nf)
#pragma unroll
        for (int rr = 0; rr < 4; ++rr) {
          int q = (((m2 << 1) + nf) << 2) + rr;
          u16 gb16 = f2bf(acc[m2][nf][rr] - zv[(m2 << 1) + nf][rr]);
          if (q < 8) h0[q] = (short)gb16; else h1[q - 8] = (short)gb16;
        }
    u16* Gs = Gp + (size_t)slot * SLOT + base;
    *(short8*)(Gs) = h0;
    *(short8*)(Gs + 8) = h1;
    const int jmax = e < 4 ? e : 4;              // valid slots this iteration
    // batched Gp loads: all old-slot payloads issued before the dots
    short8 qa[5], qb[5];
#pragma unroll
    for (int j = 0; j < 5; ++j) {
      if (j != slot && j <= jmax) {
        qa[j] = *(const short8*)(Gp + (size_t)j * SLOT + base);
        qb[j] = *(const short8*)(Gp + (size_t)j * SLOT + base + 8);
      }
    }
    float gacc[5];
#pragma unroll
    for (int j = 0; j < 5; ++j) {
      if (j > jmax) { gacc[j] = 0.f; continue; }
      if (j == slot) {
        float a = 0.f;
#pragma unroll
        for (int m2 = 0; m2 < 2; ++m2)
#pragma unroll
          for (int nf = 0; nf < 2; ++nf)
#pragma unroll
            for (int rr = 0; rr < 4; ++rr) {
              float gd = acc[m2][nf][rr] - zv[(m2 << 1) + nf][rr];
              a += gd * gd;
            }
        gacc[j] = a;
      } else {
        float a = 0.f;
#pragma unroll
        for (int m2 = 0; m2 < 2; ++m2)
#pragma unroll
          for (int nf = 0; nf < 2; ++nf)
#pragma unroll
            for (int rr = 0; rr < 4; ++rr) {
              int q = (((m2 << 1) + nf) << 2) + rr;
              float gd = acc[m2][nf][rr] - zv[(m2 << 1) + nf][rr];
              float hv = bf2f((u16)(q < 8 ? qa[j][q] : qb[j][q - 8]));
              a += gd * hv;
            }
        gacc[j] = a;
      }
    }
    float vals[7] = {gacc[0], gacc[1], gacc[2], gacc[3], gacc[4], sd, sf};
#pragma unroll
    for (int i = 0; i < 7; ++i) {
      float v = vals[i];
#pragma unroll
      for (int off = 1; off < 64; off <<= 1) v += __shfl_xor(v, off);
      if (lane == 0) red[(wv << 3) + i] = v;
    }
  }
  __syncthreads();
  if (tid < 7) {
    float s = 0.f;
#pragma unroll
    for (int w = 0; w < 4; ++w) s += red[(w << 3) + tid];
    if (tid < 5)       gpart[(size_t)lbid * 5 + tid] = s;
    else if (tid == 5) resp[lbid * 2] = s;
    else               resp[lbid * 2 + 1] = s;
  }
}

// ---------------- final: Fhp[last_slot] packed -> d_out NCHW f32
__global__ void __launch_bounds__(256) k_out(const float* __restrict__ Fhp,
    const Ctrl* __restrict__ ctrl, float* __restrict__ out)
{
  __shared__ float T[32 * 132];
  int slot = ctrl->last_slot;
  const int tid = threadIdx.x;
  const int wv = tid >> 6, lane = tid & 63;
  const int lhi = lane >> 4, llo = lane & 15;
  const int lbid = blockIdx.x;                   // 1024 = 32 images * 32 rows
  const int n = lbid >> 5, y0 = lbid & 31;
  const size_t base = (size_t)slot * SLOT + ((size_t)lbid * 256 + tid) * 16;
#pragma unroll
  for (int m2 = 0; m2 < 2; ++m2)
#pragma unroll
    for (int nf = 0; nf < 2; ++nf) {
      f32x4 v = *(const f32x4*)(Fhp + base + (((m2 << 1) + nf) << 2));
#pragma unroll
      for (int rr = 0; rr < 4; ++rr) {
        int p = (m2 << 4) + (lhi << 2) + rr;
        int ch = (wv << 5) + (nf << 4) + llo;
        T[p * 132 + ch] = v[rr];
      }
    }
  __syncthreads();
  int c = tid >> 1, h = tid & 1;
  float* ob = out + (((size_t)(n << 7) + c) << 10) + (y0 << 5) + (h << 4);
#pragma unroll
  for (int i2 = 0; i2 < 4; ++i2) {
    f32x4 v;
#pragma unroll
    for (int i = 0; i < 4; ++i) v[i] = T[((h << 4) + (i2 << 2) + i) * 132 + c];
    *(f32x4*)(ob + (i2 << 2)) = v;
  }
}

extern "C" void kernel_launch(void* const* d_in, const int* in_sizes, int n_in,
                              void* d_out, int out_size, void* d_ws, size_t ws_size,
                              hipStream_t stream) {
  const float* x    = (const float*)d_in[0];   // [32,128,32,32]
  const float* W    = (const float*)d_in[1];   // [128,128,3,3]
  const float* bias = (const float*)d_in[2];   // [128]
  const int*   mask = (const int*)d_in[3];     // [32,1,32,32]
  float* out = (float*)d_out;
  char* ws = (char*)d_ws;

  float* Fhp   = (float*)(ws + 0);             // 83,886,080 (packed f32)
  u16*   FhH   = (u16*)(ws + 83886080);        // 41,943,040 (bf16 NHWC swizzled)
  u16*   Gp    = (u16*)(ws + 125829120);       // 41,943,040 (packed bf16)
  u16*   xsw   = (u16*)(ws + 167772160);       // 8,388,608
  u16*   Wb    = (u16*)(ws + 176160768);       // 294,912
  float* gram  = (float*)(ws + 176455680);     // 3,200
  float* gpart = (float*)(ws + 176458880);     // 20,480
  float* resp  = (float*)(ws + 176479360);     // 8,192
  Ctrl*  ctrl  = (Ctrl*)(ws + 176487552);

  k_prepw<<<576, 256, 0, stream>>>(W, Wb, ctrl);
  k_prepx<<<2048, 256, 0, stream>>>(x, xsw);
  for (int e = 0; e < 50; ++e)
    k_iter<<<1024, 256, 0, stream>>>(e, xsw, mask, Wb, bias,
                                     Fhp, FhH, Gp, gram, gpart, resp, ctrl);
  k_out<<<1024, 256, 0, stream>>>(Fhp, ctrl, out);
  (void)in_sizes; (void)n_in; (void)out_size; (void)ws_size;
}